// Round 10
// baseline (5104.700 us; speedup 1.0000x reference)
//
#include <hip/hip_runtime.h>
#include <stdint.h>

#define NBATCH 64
#define TENC   1024
#define TDEC   256
#define FDIM   8
#define UDIM   256
#define GDIM   1024
#define NHEAD  8
#define DHEAD  32
#define LNEPS  1e-5f

// ext-k = 256 (U rows) + 8 (W rows) = 264 rows -> 132 f16-pairs per unit.
// Thread owns unit u -> gate cols {u,256+u,512+u,768+u}; one uint4 per pair.
// Split: 96 pairs arch-VGPR (384 regs, pinned), 36 pairs LDS (147 KB).
#define KPV 96
#define KPL 36

typedef unsigned int   u32;
typedef unsigned short u16;

typedef _Float16 half2v __attribute__((ext_vector_type(2)));

__device__ __forceinline__ float bf2f_lo(u32 w) { return __uint_as_float(w << 16); }
__device__ __forceinline__ float bf2f_hi(u32 w) { return __uint_as_float(w & 0xFFFF0000u); }
__device__ __forceinline__ u16 f2bf(float f) {
  u32 u = __float_as_uint(f);
  u = (u + 0x7FFFu + ((u >> 16) & 1u)) >> 16;
  return (u16)u;
}
__device__ __forceinline__ u16 f2h_bits(float f) {
  _Float16 h = (_Float16)f;
  return __builtin_bit_cast(u16, h);
}
__device__ __forceinline__ float fdot2p(u32 wp, u32 hp, float acc) {
  return __builtin_amdgcn_fdot2(__builtin_bit_cast(half2v, wp),
                                __builtin_bit_cast(half2v, hp), acc, false);
}
__device__ __forceinline__ float sigf(float x) { return 1.0f / (1.0f + __expf(-x)); }
__device__ __forceinline__ float tanhf_fast(float x) {
  float ax = fabsf(x);
  float e  = __expf(2.0f * ax);
  float r  = 1.0f - 2.0f / (e + 1.0f);
  return copysignf(r, x);
}

// ---------------- LayerNorm over F=8 (encoder input) ----------------
__global__ __launch_bounds__(256)
void k_ln8(const float* __restrict__ x, const float* __restrict__ g,
           const float* __restrict__ bt, float* __restrict__ y, int rows) {
  int r = blockIdx.x * blockDim.x + threadIdx.x;
  if (r >= rows) return;
  const float* xp = x + (size_t)r * 8;
  float4 a = ((const float4*)xp)[0];
  float4 b4 = ((const float4*)xp)[1];
  float v[8] = {a.x, a.y, a.z, a.w, b4.x, b4.y, b4.z, b4.w};
  float m = 0.f;
#pragma unroll
  for (int i = 0; i < 8; ++i) m += v[i];
  m *= 0.125f;
  float var = 0.f;
#pragma unroll
  for (int i = 0; i < 8; ++i) { float d = v[i] - m; var += d * d; }
  var *= 0.125f;
  float rs = rsqrtf(var + LNEPS);
  float o[8];
#pragma unroll
  for (int i = 0; i < 8; ++i) o[i] = g[i] * (v[i] - m) * rs + bt[i];
  float* yp = y + (size_t)r * 8;
  ((float4*)yp)[0] = make_float4(o[0], o[1], o[2], o[3]);
  ((float4*)yp)[1] = make_float4(o[4], o[5], o[6], o[7]);
}

// ---- pack weights: out[gp*256 + u] = uint4 over gates g=0..3 of
//      f16pair(rows 2gp,2gp+1 ; col g*256+u). Rows 0..255 = U, 256..263 = W.
__global__ __launch_bounds__(256)
void k_packUW2(const float* __restrict__ U, const float* __restrict__ W,
               uint4* __restrict__ out) {
  int idx = blockIdx.x * 256 + threadIdx.x;  // 132*256
  int gp = idx >> 8, u = idx & 255;
  int r0 = 2 * gp, r1 = 2 * gp + 1;
  const float* R0 = (r0 < 256) ? (U + (size_t)r0 * GDIM) : (W + (size_t)(r0 - 256) * GDIM);
  const float* R1 = (r1 < 256) ? (U + (size_t)r1 * GDIM) : (W + (size_t)(r1 - 256) * GDIM);
  uint4 o;
  u32* oc = (u32*)&o;
#pragma unroll
  for (int g = 0; g < 4; ++g) {
    int c = g * 256 + u;
    oc[g] = (u32)f2h_bits(R0[c]) | ((u32)f2h_bits(R1[c]) << 16);
  }
  out[idx] = o;
}

// ---------------- LSTM scan v10: 256 thr, 1 wave/SIMD, all-VGPR+LDS weights ----------------
// 64 blocks x 256 threads (4 waves = 1/SIMD -> 512-reg budget; 228 VGPRs
// proven honored in round 9 with this exact config/pinning mechanism).
// Thread u owns gate cols {u,256+u,512+u,768+u}: dot outputs ARE
// (zi,zf,zg,zo) -> no z exchange, ONE barrier per step (double-buffered h).
// Weights: 96 pairs pinned arch-VGPR (384 regs), 36 pairs LDS (147 KB ->
// 1 block/CU). NO AGPRs, NO volatile asm in the loop (round 9 lesson:
// volatile per-use reads serialize; 1 wave/SIMD cannot hide that).
#define DOT4(w4, hh)                                              \
  do {                                                            \
    a0 = fdot2p((w4).x, (hh), a0); a1 = fdot2p((w4).y, (hh), a1); \
    a2 = fdot2p((w4).z, (hh), a2); a3 = fdot2p((w4).w, (hh), a3); \
  } while (0)

__global__
__attribute__((amdgpu_flat_work_group_size(256, 256), amdgpu_waves_per_eu(1, 1)))
void k_scan10(const float* __restrict__ xseq,  // [B,T,8]
              const uint4* __restrict__ Wpk,   // [132*256] uint4
              const float* __restrict__ bias,  // [1024]
              const float* __restrict__ h0, const float* __restrict__ c0,
              float* __restrict__ seq_out,     // [B,T,256]
              float* __restrict__ hT, float* __restrict__ cT, int T) {
  __shared__ __align__(16) uint4 wl[KPL * 256];  // 147 KB
  __shared__ __align__(16) u32   hbuf[2][136];   // 1 KB double-buffered h+x pairs

  const int tid = threadIdx.x, b = blockIdx.x;

  // ---- weights: pairs 0..95 -> pinned arch VGPR, 96..131 -> LDS ----
  uint4 wv[KPV];
#pragma unroll
  for (int i = 0; i < KPV; ++i) {
    wv[i] = Wpk[i * 256 + tid];
    asm("" : "+v"(wv[i].x), "+v"(wv[i].y), "+v"(wv[i].z), "+v"(wv[i].w));
  }
#pragma unroll
  for (int i = 0; i < KPL; ++i) wl[i * 256 + tid] = Wpk[(KPV + i) * 256 + tid];

  const float bi = bias[tid], bf = bias[256 + tid], bg = bias[512 + tid],
              bo = bias[768 + tid];

  // ---- init state (buffer 0) ----
  float c_reg = c0 ? c0[b * 256 + tid] : 0.f;
  float h_last = h0 ? h0[b * 256 + tid] : 0.f;
  ((u16*)hbuf[0])[tid] = f2h_bits(h_last);
  if (tid < 8) {
    float xv = xseq[(size_t)(b * T) * 8 + tid];
    ((u16*)hbuf[0])[256 + tid] = f2h_bits(xv);
  }
  __syncthreads();

  for (int t = 0; t < T; ++t) {
    const int pr = t & 1, nx = pr ^ 1;
    // x prefetch for t+1 (threads 0-7) — latency hides under the dots
    float xn = 0.f;
    if (tid < 8) {
      int t2 = (t + 1 < T) ? (t + 1) : (T - 1);
      xn = xseq[(size_t)(b * T + t2) * 8 + tid];
    }
    // ---- dot phase: 132 pairs, outputs are (zi,zf,zg,zo) directly ----
    float a0 = bi, a1 = bf, a2 = bg, a3 = bo;
    const uint4* hq4 = (const uint4*)hbuf[pr];
#pragma unroll
    for (int q = 0; q < 24; ++q) {  // pairs 0..95 (arch VGPR)
      uint4 hh = hq4[q];
      DOT4(wv[4 * q + 0], hh.x);
      DOT4(wv[4 * q + 1], hh.y);
      DOT4(wv[4 * q + 2], hh.z);
      DOT4(wv[4 * q + 3], hh.w);
    }
#pragma unroll
    for (int q = 0; q < 9; ++q) {   // pairs 96..131 (LDS; incl. x rows)
      uint4 hh = hq4[24 + q];
      uint4 w0 = wl[(4 * q + 0) * 256 + tid];
      uint4 w1 = wl[(4 * q + 1) * 256 + tid];
      uint4 w2 = wl[(4 * q + 2) * 256 + tid];
      uint4 w3 = wl[(4 * q + 3) * 256 + tid];
      DOT4(w0, hh.x);
      DOT4(w1, hh.y);
      DOT4(w2, hh.z);
      DOT4(w3, hh.w);
    }
    // ---- gate (every thread: its own unit) ----
    float ig = sigf(a0), fg = sigf(a1);
    float gg = tanhf_fast(a2), og = sigf(a3);
    c_reg = fg * c_reg + ig * gg;
    float h = og * tanhf_fast(c_reg);
    h_last = h;
    seq_out[(size_t)(b * T + t) * 256 + tid] = h;
    ((u16*)hbuf[nx])[tid] = f2h_bits(h);
    if (tid < 8) ((u16*)hbuf[nx])[256 + tid] = f2h_bits(xn);
    __syncthreads();  // one barrier per step
  }
  if (hT) {
    hT[b * 256 + tid] = h_last;
    cT[b * 256 + tid] = c_reg;
  }
}

// ---------------- GEMM: C[M,256] = A[M,256] @ B[256,256] + bias ----------------
template <int OMODE>
__global__ __launch_bounds__(256)
void k_gemm256(const float* __restrict__ A, const float* __restrict__ Bw,
               const float* __restrict__ bias, void* __restrict__ outp,
               int M, int Tdim) {
  __shared__ __align__(16) float As[16][68];
  __shared__ __align__(16) float Bs[16][68];
  const int tid = threadIdx.x;
  const int tx = tid & 15, ty = tid >> 4;
  const int bm = blockIdx.x * 64, bn = blockIdx.y * 64;
  const int ar = tid >> 2, ac = (tid & 3) << 2;
  const int br = tid >> 4, bc = (tid & 15) << 2;
  float acc[4][4] = {};
  for (int k0 = 0; k0 < 256; k0 += 16) {
    float4 av = *(const float4*)(A + (size_t)(bm + ar) * 256 + k0 + ac);
    As[ac + 0][ar] = av.x; As[ac + 1][ar] = av.y;
    As[ac + 2][ar] = av.z; As[ac + 3][ar] = av.w;
    float4 bv = *(const float4*)(Bw + (size_t)(k0 + br) * 256 + bn + bc);
    *(float4*)&Bs[br][bc] = bv;
    __syncthreads();
#pragma unroll
    for (int k = 0; k < 16; ++k) {
      float4 a4 = *(const float4*)&As[k][ty << 2];
      float4 b4 = *(const float4*)&Bs[k][tx << 2];
      float aa[4] = {a4.x, a4.y, a4.z, a4.w};
      float bb[4] = {b4.x, b4.y, b4.z, b4.w};
#pragma unroll
      for (int i = 0; i < 4; ++i)
#pragma unroll
        for (int jj = 0; jj < 4; ++jj)
          acc[i][jj] = fmaf(aa[i], bb[jj], acc[i][jj]);
    }
    __syncthreads();
  }
#pragma unroll
  for (int i = 0; i < 4; ++i) {
    int mm = bm + (ty << 2) + i;
#pragma unroll
    for (int jj = 0; jj < 4; ++jj) {
      int n = bn + (tx << 2) + jj;
      float v = acc[i][jj] + bias[n];
      if (OMODE == 0) {
        ((float*)outp)[(size_t)mm * 256 + n] = v;
      } else {
        int bb_ = mm / Tdim, t = mm % Tdim;
        int hh = n >> 5, dd = n & 31;
        size_t o = ((((size_t)bb_ * NHEAD + hh) * Tdim) + t) * 32 + dd;
        if (OMODE == 1) ((float*)outp)[o] = v;
        else            ((u16*)outp)[o]   = f2bf(v);
      }
    }
  }
}

// ---------------- attention: one block per (b,h); thread = q row ----------------
__global__ __launch_bounds__(256)
void k_attn(const float* __restrict__ Q, const u16* __restrict__ Kb,
            const u16* __restrict__ Vb, float* __restrict__ ctx) {
  const int bh = blockIdx.x;
  const int b = bh >> 3, h = bh & 7;
  const int tid = threadIdx.x;
  __shared__ __align__(16) float Kl[64][36];
  __shared__ __align__(16) float Vl[64][36];
  float q[32];
  {
    const float* qp = Q + ((size_t)bh * TDEC + tid) * 32;
#pragma unroll
    for (int i = 0; i < 8; ++i) {
      float4 v = ((const float4*)qp)[i];
      q[i * 4 + 0] = v.x * 0.17677669529663687f;
      q[i * 4 + 1] = v.y * 0.17677669529663687f;
      q[i * 4 + 2] = v.z * 0.17677669529663687f;
      q[i * 4 + 3] = v.w * 0.17677669529663687f;
    }
  }
  float mrun = -3.0e38f, lrun = 0.f;
  float acc[32];
#pragma unroll
  for (int i = 0; i < 32; ++i) acc[i] = 0.f;
  const int lr = tid >> 2, lc = (tid & 3) << 3;
  for (int kt = 0; kt < TENC; kt += 64) {
    {
      uint4 kw = *(const uint4*)(Kb + ((size_t)bh * TENC + kt + lr) * 32 + lc);
      Kl[lr][lc + 0] = bf2f_lo(kw.x); Kl[lr][lc + 1] = bf2f_hi(kw.x);
      Kl[lr][lc + 2] = bf2f_lo(kw.y); Kl[lr][lc + 3] = bf2f_hi(kw.y);
      Kl[lr][lc + 4] = bf2f_lo(kw.z); Kl[lr][lc + 5] = bf2f_hi(kw.z);
      Kl[lr][lc + 6] = bf2f_lo(kw.w); Kl[lr][lc + 7] = bf2f_hi(kw.w);
      uint4 vw = *(const uint4*)(Vb + ((size_t)bh * TENC + kt + lr) * 32 + lc);
      Vl[lr][lc + 0] = bf2f_lo(vw.x); Vl[lr][lc + 1] = bf2f_hi(vw.x);
      Vl[lr][lc + 2] = bf2f_lo(vw.y); Vl[lr][lc + 3] = bf2f_hi(vw.y);
      Vl[lr][lc + 4] = bf2f_lo(vw.z); Vl[lr][lc + 5] = bf2f_hi(vw.z);
      Vl[lr][lc + 6] = bf2f_lo(vw.w); Vl[lr][lc + 7] = bf2f_hi(vw.w);
    }
    __syncthreads();
#pragma unroll
    for (int cch = 0; cch < 8; ++cch) {
      float s8[8];
#pragma unroll
      for (int i = 0; i < 8; ++i) {
        const float4* kr = (const float4*)&Kl[cch * 8 + i][0];
        float ss = 0.f;
#pragma unroll
        for (int d4 = 0; d4 < 8; ++d4) {
          float4 kv = kr[d4];
          ss = fmaf(q[d4 * 4 + 0], kv.x, ss);
          ss = fmaf(q[d4 * 4 + 1], kv.y, ss);
          ss = fmaf(q[d4 * 4 + 2], kv.z, ss);
          ss = fmaf(q[d4 * 4 + 3], kv.w, ss);
        }
        s8[i] = ss;
      }
      float mnew = mrun;
#pragma unroll
      for (int i = 0; i < 8; ++i) mnew = fmaxf(mnew, s8[i]);
      float sc = __expf(mrun - mnew);
      mrun = mnew;
      lrun *= sc;
#pragma unroll
      for (int d = 0; d < 32; ++d) acc[d] *= sc;
#pragma unroll
      for (int i = 0; i < 8; ++i) {
        float p = __expf(s8[i] - mnew);
        lrun += p;
        const float4* vr = (const float4*)&Vl[cch * 8 + i][0];
#pragma unroll
        for (int d4 = 0; d4 < 8; ++d4) {
          float4 vv = vr[d4];
          acc[d4 * 4 + 0] = fmaf(p, vv.x, acc[d4 * 4 + 0]);
          acc[d4 * 4 + 1] = fmaf(p, vv.y, acc[d4 * 4 + 1]);
          acc[d4 * 4 + 2] = fmaf(p, vv.z, acc[d4 * 4 + 2]);
          acc[d4 * 4 + 3] = fmaf(p, vv.w, acc[d4 * 4 + 3]);
        }
      }
    }
    __syncthreads();
  }
  float inv = 1.0f / lrun;
  float* op = ctx + ((size_t)(b * TDEC + tid) * 256 + h * 32);
#pragma unroll
  for (int i = 0; i < 8; ++i) {
    ((float4*)op)[i] = make_float4(acc[i * 4 + 0] * inv, acc[i * 4 + 1] * inv,
                                   acc[i * 4 + 2] * inv, acc[i * 4 + 3] * inv);
  }
}

// ---------------- final: LN(dec_seq + ctxo) @ W_out + b_out ----------------
__global__ __launch_bounds__(256)
void k_final(const float* __restrict__ dec_seq, const float* __restrict__ ctxo,
             const float* __restrict__ g, const float* __restrict__ bb,
             const float* __restrict__ Wout, const float* __restrict__ bout,
             float* __restrict__ out) {
  const int wv = threadIdx.x >> 6, lane = threadIdx.x & 63;
  const int row = blockIdx.x * 4 + wv;
  const size_t base = (size_t)row * 256 + lane * 4;
  float4 dv = *(const float4*)(dec_seq + base);
  float4 cv = *(const float4*)(ctxo + base);
  float v[4] = {dv.x + cv.x, dv.y + cv.y, dv.z + cv.z, dv.w + cv.w};
  float s = v[0] + v[1] + v[2] + v[3];
#pragma unroll
  for (int off = 32; off >= 1; off >>= 1) s += __shfl_xor(s, off, 64);
  float m = s * (1.0f / 256.0f);
  float d2 = 0.f;
#pragma unroll
  for (int i = 0; i < 4; ++i) { float d = v[i] - m; d2 += d * d; }
#pragma unroll
  for (int off = 32; off >= 1; off >>= 1) d2 += __shfl_xor(d2, off, 64);
  float rs = rsqrtf(d2 * (1.0f / 256.0f) + LNEPS);
  float4 g4 = *(const float4*)(g + lane * 4);
  float4 b4 = *(const float4*)(bb + lane * 4);
  float4 w4 = *(const float4*)(Wout + lane * 4);
  float mix0 = g4.x * (v[0] - m) * rs + b4.x;
  float mix1 = g4.y * (v[1] - m) * rs + b4.y;
  float mix2 = g4.z * (v[2] - m) * rs + b4.z;
  float mix3 = g4.w * (v[3] - m) * rs + b4.w;
  float p = mix0 * w4.x + mix1 * w4.y + mix2 * w4.z + mix3 * w4.w;
#pragma unroll
  for (int off = 32; off >= 1; off >>= 1) p += __shfl_xor(p, off, 64);
  if (lane == 0) out[row] = p + bout[0];
}

extern "C" void kernel_launch(void* const* d_in, const int* in_sizes, int n_in,
                              void* d_out, int out_size, void* d_ws, size_t ws_size,
                              hipStream_t stream) {
  const float* enc_in   = (const float*)d_in[0];
  const float* dec_in   = (const float*)d_in[1];
  const float* ln_enc_g = (const float*)d_in[2];
  const float* ln_enc_b = (const float*)d_in[3];
  const float* W_enc    = (const float*)d_in[4];
  const float* U_enc    = (const float*)d_in[5];
  const float* b_enc    = (const float*)d_in[6];
  const float* W_dec    = (const float*)d_in[7];
  const float* U_dec    = (const float*)d_in[8];
  const float* b_dec    = (const float*)d_in[9];
  const float* Wq = (const float*)d_in[10]; const float* bq = (const float*)d_in[11];
  const float* Wk = (const float*)d_in[12]; const float* bk = (const float*)d_in[13];
  const float* Wv = (const float*)d_in[14]; const float* bv = (const float*)d_in[15];
  const float* Wo = (const float*)d_in[16]; const float* bo = (const float*)d_in[17];
  const float* ln_post_g = (const float*)d_in[18];
  const float* ln_post_b = (const float*)d_in[19];
  const float* W_out     = (const float*)d_in[20];
  const float* b_out     = (const float*)d_in[21];

  char* ws = (char*)d_ws;
  size_t off = 0;
  auto alloc = [&](size_t bytes) -> void* {
    void* p = ws + off;
    off += (bytes + 255) & ~(size_t)255;
    return p;
  };
  float* xln     = (float*)alloc((size_t)NBATCH * TENC * 8 * 4);
  uint4* upkE    = (uint4*)alloc((size_t)132 * 256 * 16);
  uint4* upkD    = (uint4*)alloc((size_t)132 * 256 * 16);
  float* enc_seq = (float*)alloc((size_t)NBATCH * TENC * 256 * 4);
  float* dec_seq = (float*)alloc((size_t)NBATCH * TDEC * 256 * 4);
  float* hfin    = (float*)alloc((size_t)NBATCH * 256 * 4);
  float* cfin    = (float*)alloc((size_t)NBATCH * 256 * 4);
  float* Qp      = (float*)alloc((size_t)NBATCH * NHEAD * TDEC * 32 * 4);
  u16*   Kb      = (u16*)  alloc((size_t)NBATCH * NHEAD * TENC * 32 * 2);
  u16*   Vb      = (u16*)  alloc((size_t)NBATCH * NHEAD * TENC * 32 * 2);
  float* ctx     = (float*)alloc((size_t)NBATCH * TDEC * 256 * 4);
  float* ctxo    = (float*)alloc((size_t)NBATCH * TDEC * 256 * 4);

  // 1. LN on encoder input
  k_ln8<<<dim3(256), dim3(256), 0, stream>>>(enc_in, ln_enc_g, ln_enc_b, xln,
                                             NBATCH * TENC);
  // 2. pack [U;W] -> per-unit gate-quad f16 pairs
  k_packUW2<<<dim3(132), dim3(256), 0, stream>>>(U_enc, W_enc, upkE);
  k_packUW2<<<dim3(132), dim3(256), 0, stream>>>(U_dec, W_dec, upkD);
  // 3. encoder scan
  k_scan10<<<dim3(NBATCH), dim3(256), 0, stream>>>(
      xln, upkE, b_enc, nullptr, nullptr, enc_seq, hfin, cfin, TENC);
  // 4. decoder scan
  k_scan10<<<dim3(NBATCH), dim3(256), 0, stream>>>(
      dec_in, upkD, b_dec, hfin, cfin, dec_seq, nullptr, nullptr, TDEC);
  // 5. projections
  k_gemm256<1><<<dim3(256, 4), dim3(256), 0, stream>>>(dec_seq, Wq, bq, Qp, NBATCH * TDEC, TDEC);
  k_gemm256<2><<<dim3(1024, 4), dim3(256), 0, stream>>>(enc_seq, Wk, bk, Kb, NBATCH * TENC, TENC);
  k_gemm256<2><<<dim3(1024, 4), dim3(256), 0, stream>>>(enc_seq, Wv, bv, Vb, NBATCH * TENC, TENC);
  // 6. attention
  k_attn<<<dim3(NBATCH * NHEAD), dim3(256), 0, stream>>>(Qp, Kb, Vb, ctx);
  // 7. output projection
  k_gemm256<0><<<dim3(256, 4), dim3(256), 0, stream>>>(ctx, Wo, bo, ctxo, NBATCH * TDEC, 0x7fffffff);
  // 8. residual + LN + final dot
  k_final<<<dim3(NBATCH * TDEC / 4), dim3(256), 0, stream>>>(
      dec_seq, ctxo, ln_post_g, ln_post_b, W_out, b_out, (float*)d_out);
}

// Round 11
// 3452.938 us; speedup vs baseline: 1.4784x; 1.4784x over previous
//
#include <hip/hip_runtime.h>
#include <stdint.h>

#define NBATCH 64
#define TENC   1024
#define TDEC   256
#define FDIM   8
#define UDIM   256
#define GDIM   1024
#define NHEAD  8
#define DHEAD  32
#define LNEPS  1e-5f

// ext-k = 256 (U rows) + 8 (W rows) = 264 rows -> 132 f16-pairs = 33 quads/col.
// Per thread: 2 columns. Split per column: 9 quads pinned VGPR, 9 LDS, 15 L2-stream.
#define KQ   33
#define KPIN 9
#define KLDS 9
#define KSTR 15

typedef unsigned int   u32;
typedef unsigned short u16;

typedef _Float16 half2v __attribute__((ext_vector_type(2)));

__device__ __forceinline__ float bf2f_lo(u32 w) { return __uint_as_float(w << 16); }
__device__ __forceinline__ float bf2f_hi(u32 w) { return __uint_as_float(w & 0xFFFF0000u); }
__device__ __forceinline__ u16 f2bf(float f) {
  u32 u = __float_as_uint(f);
  u = (u + 0x7FFFu + ((u >> 16) & 1u)) >> 16;
  return (u16)u;
}
__device__ __forceinline__ u16 f2h_bits(float f) {
  _Float16 h = (_Float16)f;
  return __builtin_bit_cast(u16, h);
}
__device__ __forceinline__ float fdot2p(u32 wp, u32 hp, float acc) {
  return __builtin_amdgcn_fdot2(__builtin_bit_cast(half2v, wp),
                                __builtin_bit_cast(half2v, hp), acc, false);
}
__device__ __forceinline__ float sigf(float x) { return 1.0f / (1.0f + __expf(-x)); }
__device__ __forceinline__ float tanhf_fast(float x) {
  float ax = fabsf(x);
  float e  = __expf(2.0f * ax);
  float r  = 1.0f - 2.0f / (e + 1.0f);
  return copysignf(r, x);
}

// ---------------- LayerNorm over F=8 (encoder input) ----------------
__global__ __launch_bounds__(256)
void k_ln8(const float* __restrict__ x, const float* __restrict__ g,
           const float* __restrict__ bt, float* __restrict__ y, int rows) {
  int r = blockIdx.x * blockDim.x + threadIdx.x;
  if (r >= rows) return;
  const float* xp = x + (size_t)r * 8;
  float4 a = ((const float4*)xp)[0];
  float4 b4 = ((const float4*)xp)[1];
  float v[8] = {a.x, a.y, a.z, a.w, b4.x, b4.y, b4.z, b4.w};
  float m = 0.f;
#pragma unroll
  for (int i = 0; i < 8; ++i) m += v[i];
  m *= 0.125f;
  float var = 0.f;
#pragma unroll
  for (int i = 0; i < 8; ++i) { float d = v[i] - m; var += d * d; }
  var *= 0.125f;
  float rs = rsqrtf(var + LNEPS);
  float o[8];
#pragma unroll
  for (int i = 0; i < 8; ++i) o[i] = g[i] * (v[i] - m) * rs + bt[i];
  float* yp = y + (size_t)r * 8;
  ((float4*)yp)[0] = make_float4(o[0], o[1], o[2], o[3]);
  ((float4*)yp)[1] = make_float4(o[4], o[5], o[6], o[7]);
}

// ---- pack: out[q*1024 + col] = uint4 of f16-pairs {4q..4q+3} for column col.
//      pair p covers ext rows {2p, 2p+1}; rows 0..255 = U, 256..263 = W.
__global__ __launch_bounds__(256)
void k_packUW3(const float* __restrict__ U, const float* __restrict__ W,
               uint4* __restrict__ out) {
  int idx = blockIdx.x * 256 + threadIdx.x;  // 33*1024 = 33792
  if (idx >= KQ * GDIM) return;
  int q = idx >> 10, col = idx & 1023;
  uint4 o;
  u32* oc = (u32*)&o;
#pragma unroll
  for (int c = 0; c < 4; ++c) {
    int p = 4 * q + c;
    int r0 = 2 * p, r1 = 2 * p + 1;
    float f0 = (r0 < 256) ? U[(size_t)r0 * GDIM + col] : W[(size_t)(r0 - 256) * GDIM + col];
    float f1 = (r1 < 256) ? U[(size_t)r1 * GDIM + col] : W[(size_t)(r1 - 256) * GDIM + col];
    oc[c] = (u32)f2h_bits(f0) | ((u32)f2h_bits(f1) << 16);
  }
  out[idx] = o;
}

// ---------------- LSTM scan v11: 512 thr, 2 waves/SIMD, no-spill split ----------------
// 64 blocks x 512 threads (8 waves = 2/SIMD -> grant 128 VGPR, proven round 8).
// Thread owns cols {tid, tid+512}. Per col: 9 quads pinned VGPR (72 regs total
// demand ~122 <= 128: FIRST no-spill config), 9 quads LDS (147 KB -> 1 blk/CU),
// 15 quads deliberately streamed from L2 each step (245 KB/step vs round-4's
// 384 KB). 2 waves/SIMD hide the stream latency. Two barriers/step.
#define DOTP(w4, hh)                                              \
  do {                                                            \
    a0 = fdot2p((w4).x, (hh).x, a0);                              \
    a1 = fdot2p((w4).y, (hh).y, a1);                              \
    a2 = fdot2p((w4).z, (hh).z, a2);                              \
    a3 = fdot2p((w4).w, (hh).w, a3);                              \
  } while (0)
#define DOTQ(w4, hh)                                              \
  do {                                                            \
    d0 = fdot2p((w4).x, (hh).x, d0);                              \
    d1 = fdot2p((w4).y, (hh).y, d1);                              \
    d2 = fdot2p((w4).z, (hh).z, d2);                              \
    d3 = fdot2p((w4).w, (hh).w, d3);                              \
  } while (0)

__global__
__attribute__((amdgpu_flat_work_group_size(512, 512), amdgpu_waves_per_eu(2, 2)))
void k_scan11(const float* __restrict__ xseq,  // [B,T,8]
              const uint4* __restrict__ Wpk,   // [33*1024]
              const float* __restrict__ bias,  // [1024]
              const float* __restrict__ h0, const float* __restrict__ c0,
              float* __restrict__ seq_out,     // [B,T,256]
              float* __restrict__ hT, float* __restrict__ cT, int T) {
  __shared__ __align__(16) uint4 wl[2 * KLDS][512];  // 147456 B
  __shared__ float zl[1024];                         // 4 KB
  __shared__ __align__(16) u32 hbuf[2][136];         // 1 KB double-buffered h+x pairs

  const int tid = threadIdx.x, b = blockIdx.x;
  const int cA = tid, cB = tid + 512;

  // ---- weights: 9 quads/col pinned VGPR, 9 quads/col LDS; 15/col streamed ----
  uint4 wpA[KPIN], wpB[KPIN];
#pragma unroll
  for (int i = 0; i < KPIN; ++i) {
    wpA[i] = Wpk[(i << 10) + cA];
    asm("" : "+v"(wpA[i].x), "+v"(wpA[i].y), "+v"(wpA[i].z), "+v"(wpA[i].w));
    wpB[i] = Wpk[(i << 10) + cB];
    asm("" : "+v"(wpB[i].x), "+v"(wpB[i].y), "+v"(wpB[i].z), "+v"(wpB[i].w));
  }
#pragma unroll
  for (int i = 0; i < KLDS; ++i) {
    wl[i][tid]        = Wpk[((KPIN + i) << 10) + cA];
    wl[KLDS + i][tid] = Wpk[((KPIN + i) << 10) + cB];
  }
  const uint4* wstr = Wpk + ((KPIN + KLDS) << 10);  // streamed base (quads 18..32)

  const float bA = bias[cA], bB = bias[cB];

  // ---- state init (buffer 0) ----
  float c_reg = 0.f, h_last = 0.f;
  if (tid < 256) {
    c_reg  = c0 ? c0[b * 256 + tid] : 0.f;
    h_last = h0 ? h0[b * 256 + tid] : 0.f;
    ((u16*)hbuf[0])[tid] = f2h_bits(h_last);
  }
  if (tid >= 256 && tid < 264) {
    float xv = xseq[(size_t)(b * T) * 8 + (tid - 256)];
    ((u16*)hbuf[0])[tid] = f2h_bits(xv);
  }
  __syncthreads();

  for (int t = 0; t < T; ++t) {
    const int pr = t & 1, nx = pr ^ 1;
    // x prefetch for t+1 (threads 256-263) — hides under the dots
    float xn = 0.f;
    if (tid >= 256 && tid < 264) {
      int t2 = (t + 1 < T) ? (t + 1) : (T - 1);
      xn = xseq[(size_t)(b * T + t2) * 8 + (tid - 256)];
    }
    // ---- dot phase: 33 quads x 2 cols; h quads are wave-uniform broadcasts ----
    float a0 = bA, a1 = 0.f, a2 = 0.f, a3 = 0.f;  // col A
    float d0 = bB, d1 = 0.f, d2 = 0.f, d3 = 0.f;  // col B
    const uint4* hq4 = (const uint4*)hbuf[pr];
#pragma unroll
    for (int q = 0; q < KPIN; ++q) {  // quads 0..8 (pinned VGPR)
      uint4 hh = hq4[q];
      DOTP(wpA[q], hh);
      DOTQ(wpB[q], hh);
    }
#pragma unroll
    for (int q = 0; q < KLDS; ++q) {  // quads 9..17 (LDS)
      uint4 hh = hq4[KPIN + q];
      uint4 wA = wl[q][tid];
      uint4 wB = wl[KLDS + q][tid];
      DOTP(wA, hh);
      DOTQ(wB, hh);
    }
#pragma unroll
    for (int q = 0; q < KSTR; ++q) {  // quads 18..32 (deliberate L2 stream)
      uint4 hh = hq4[KPIN + KLDS + q];
      uint4 wA = wstr[(q << 10) + cA];
      uint4 wB = wstr[(q << 10) + cB];
      DOTP(wA, hh);
      DOTQ(wB, hh);
    }
    zl[cA] = (a0 + a1) + (a2 + a3);
    zl[cB] = (d0 + d1) + (d2 + d3);
    __syncthreads();

    // ---- gate phase (threads 0-255: unit u = tid) ----
    if (tid < 256) {
      float zi = zl[tid], zf = zl[256 + tid], zg = zl[512 + tid], zo = zl[768 + tid];
      float ig = sigf(zi), fg = sigf(zf);
      float gg = tanhf_fast(zg), og = sigf(zo);
      c_reg = fg * c_reg + ig * gg;
      float h = og * tanhf_fast(c_reg);
      h_last = h;
      seq_out[(size_t)(b * T + t) * 256 + tid] = h;
      ((u16*)hbuf[nx])[tid] = f2h_bits(h);
    }
    if (tid >= 256 && tid < 264) ((u16*)hbuf[nx])[tid] = f2h_bits(xn);
    __syncthreads();
  }
  if (hT && tid < 256) {
    hT[b * 256 + tid] = h_last;
    cT[b * 256 + tid] = c_reg;
  }
}

// ---------------- GEMM: C[M,256] = A[M,256] @ B[256,256] + bias ----------------
template <int OMODE>
__global__ __launch_bounds__(256)
void k_gemm256(const float* __restrict__ A, const float* __restrict__ Bw,
               const float* __restrict__ bias, void* __restrict__ outp,
               int M, int Tdim) {
  __shared__ __align__(16) float As[16][68];
  __shared__ __align__(16) float Bs[16][68];
  const int tid = threadIdx.x;
  const int tx = tid & 15, ty = tid >> 4;
  const int bm = blockIdx.x * 64, bn = blockIdx.y * 64;
  const int ar = tid >> 2, ac = (tid & 3) << 2;
  const int br = tid >> 4, bc = (tid & 15) << 2;
  float acc[4][4] = {};
  for (int k0 = 0; k0 < 256; k0 += 16) {
    float4 av = *(const float4*)(A + (size_t)(bm + ar) * 256 + k0 + ac);
    As[ac + 0][ar] = av.x; As[ac + 1][ar] = av.y;
    As[ac + 2][ar] = av.z; As[ac + 3][ar] = av.w;
    float4 bv = *(const float4*)(Bw + (size_t)(k0 + br) * 256 + bn + bc);
    *(float4*)&Bs[br][bc] = bv;
    __syncthreads();
#pragma unroll
    for (int k = 0; k < 16; ++k) {
      float4 a4 = *(const float4*)&As[k][ty << 2];
      float4 b4 = *(const float4*)&Bs[k][tx << 2];
      float aa[4] = {a4.x, a4.y, a4.z, a4.w};
      float bb[4] = {b4.x, b4.y, b4.z, b4.w};
#pragma unroll
      for (int i = 0; i < 4; ++i)
#pragma unroll
        for (int jj = 0; jj < 4; ++jj)
          acc[i][jj] = fmaf(aa[i], bb[jj], acc[i][jj]);
    }
    __syncthreads();
  }
#pragma unroll
  for (int i = 0; i < 4; ++i) {
    int mm = bm + (ty << 2) + i;
#pragma unroll
    for (int jj = 0; jj < 4; ++jj) {
      int n = bn + (tx << 2) + jj;
      float v = acc[i][jj] + bias[n];
      if (OMODE == 0) {
        ((float*)outp)[(size_t)mm * 256 + n] = v;
      } else {
        int bb_ = mm / Tdim, t = mm % Tdim;
        int hh = n >> 5, dd = n & 31;
        size_t o = ((((size_t)bb_ * NHEAD + hh) * Tdim) + t) * 32 + dd;
        if (OMODE == 1) ((float*)outp)[o] = v;
        else            ((u16*)outp)[o]   = f2bf(v);
      }
    }
  }
}

// ---------------- attention: one block per (b,h); thread = q row ----------------
__global__ __launch_bounds__(256)
void k_attn(const float* __restrict__ Q, const u16* __restrict__ Kb,
            const u16* __restrict__ Vb, float* __restrict__ ctx) {
  const int bh = blockIdx.x;
  const int b = bh >> 3, h = bh & 7;
  const int tid = threadIdx.x;
  __shared__ __align__(16) float Kl[64][36];
  __shared__ __align__(16) float Vl[64][36];
  float q[32];
  {
    const float* qp = Q + ((size_t)bh * TDEC + tid) * 32;
#pragma unroll
    for (int i = 0; i < 8; ++i) {
      float4 v = ((const float4*)qp)[i];
      q[i * 4 + 0] = v.x * 0.17677669529663687f;
      q[i * 4 + 1] = v.y * 0.17677669529663687f;
      q[i * 4 + 2] = v.z * 0.17677669529663687f;
      q[i * 4 + 3] = v.w * 0.17677669529663687f;
    }
  }
  float mrun = -3.0e38f, lrun = 0.f;
  float acc[32];
#pragma unroll
  for (int i = 0; i < 32; ++i) acc[i] = 0.f;
  const int lr = tid >> 2, lc = (tid & 3) << 3;
  for (int kt = 0; kt < TENC; kt += 64) {
    {
      uint4 kw = *(const uint4*)(Kb + ((size_t)bh * TENC + kt + lr) * 32 + lc);
      Kl[lr][lc + 0] = bf2f_lo(kw.x); Kl[lr][lc + 1] = bf2f_hi(kw.x);
      Kl[lr][lc + 2] = bf2f_lo(kw.y); Kl[lr][lc + 3] = bf2f_hi(kw.y);
      Kl[lr][lc + 4] = bf2f_lo(kw.z); Kl[lr][lc + 5] = bf2f_hi(kw.z);
      Kl[lr][lc + 6] = bf2f_lo(kw.w); Kl[lr][lc + 7] = bf2f_hi(kw.w);
      uint4 vw = *(const uint4*)(Vb + ((size_t)bh * TENC + kt + lr) * 32 + lc);
      Vl[lr][lc + 0] = bf2f_lo(vw.x); Vl[lr][lc + 1] = bf2f_hi(vw.x);
      Vl[lr][lc + 2] = bf2f_lo(vw.y); Vl[lr][lc + 3] = bf2f_hi(vw.y);
      Vl[lr][lc + 4] = bf2f_lo(vw.z); Vl[lr][lc + 5] = bf2f_hi(vw.z);
      Vl[lr][lc + 6] = bf2f_lo(vw.w); Vl[lr][lc + 7] = bf2f_hi(vw.w);
    }
    __syncthreads();
#pragma unroll
    for (int cch = 0; cch < 8; ++cch) {
      float s8[8];
#pragma unroll
      for (int i = 0; i < 8; ++i) {
        const float4* kr = (const float4*)&Kl[cch * 8 + i][0];
        float ss = 0.f;
#pragma unroll
        for (int d4 = 0; d4 < 8; ++d4) {
          float4 kv = kr[d4];
          ss = fmaf(q[d4 * 4 + 0], kv.x, ss);
          ss = fmaf(q[d4 * 4 + 1], kv.y, ss);
          ss = fmaf(q[d4 * 4 + 2], kv.z, ss);
          ss = fmaf(q[d4 * 4 + 3], kv.w, ss);
        }
        s8[i] = ss;
      }
      float mnew = mrun;
#pragma unroll
      for (int i = 0; i < 8; ++i) mnew = fmaxf(mnew, s8[i]);
      float sc = __expf(mrun - mnew);
      mrun = mnew;
      lrun *= sc;
#pragma unroll
      for (int d = 0; d < 32; ++d) acc[d] *= sc;
#pragma unroll
      for (int i = 0; i < 8; ++i) {
        float p = __expf(s8[i] - mnew);
        lrun += p;
        const float4* vr = (const float4*)&Vl[cch * 8 + i][0];
#pragma unroll
        for (int d4 = 0; d4 < 8; ++d4) {
          float4 vv = vr[d4];
          acc[d4 * 4 + 0] = fmaf(p, vv.x, acc[d4 * 4 + 0]);
          acc[d4 * 4 + 1] = fmaf(p, vv.y, acc[d4 * 4 + 1]);
          acc[d4 * 4 + 2] = fmaf(p, vv.z, acc[d4 * 4 + 2]);
          acc[d4 * 4 + 3] = fmaf(p, vv.w, acc[d4 * 4 + 3]);
        }
      }
    }
    __syncthreads();
  }
  float inv = 1.0f / lrun;
  float* op = ctx + ((size_t)(b * TDEC + tid) * 256 + h * 32);
#pragma unroll
  for (int i = 0; i < 8; ++i) {
    ((float4*)op)[i] = make_float4(acc[i * 4 + 0] * inv, acc[i * 4 + 1] * inv,
                                   acc[i * 4 + 2] * inv, acc[i * 4 + 3] * inv);
  }
}

// ---------------- final: LN(dec_seq + ctxo) @ W_out + b_out ----------------
__global__ __launch_bounds__(256)
void k_final(const float* __restrict__ dec_seq, const float* __restrict__ ctxo,
             const float* __restrict__ g, const float* __restrict__ bb,
             const float* __restrict__ Wout, const float* __restrict__ bout,
             float* __restrict__ out) {
  const int wv = threadIdx.x >> 6, lane = threadIdx.x & 63;
  const int row = blockIdx.x * 4 + wv;
  const size_t base = (size_t)row * 256 + lane * 4;
  float4 dv = *(const float4*)(dec_seq + base);
  float4 cv = *(const float4*)(ctxo + base);
  float v[4] = {dv.x + cv.x, dv.y + cv.y, dv.z + cv.z, dv.w + cv.w};
  float s = v[0] + v[1] + v[2] + v[3];
#pragma unroll
  for (int off = 32; off >= 1; off >>= 1) s += __shfl_xor(s, off, 64);
  float m = s * (1.0f / 256.0f);
  float d2 = 0.f;
#pragma unroll
  for (int i = 0; i < 4; ++i) { float d = v[i] - m; d2 += d * d; }
#pragma unroll
  for (int off = 32; off >= 1; off >>= 1) d2 += __shfl_xor(d2, off, 64);
  float rs = rsqrtf(d2 * (1.0f / 256.0f) + LNEPS);
  float4 g4 = *(const float4*)(g + lane * 4);
  float4 b4 = *(const float4*)(bb + lane * 4);
  float4 w4 = *(const float4*)(Wout + lane * 4);
  float mix0 = g4.x * (v[0] - m) * rs + b4.x;
  float mix1 = g4.y * (v[1] - m) * rs + b4.y;
  float mix2 = g4.z * (v[2] - m) * rs + b4.z;
  float mix3 = g4.w * (v[3] - m) * rs + b4.w;
  float p = mix0 * w4.x + mix1 * w4.y + mix2 * w4.z + mix3 * w4.w;
#pragma unroll
  for (int off = 32; off >= 1; off >>= 1) p += __shfl_xor(p, off, 64);
  if (lane == 0) out[row] = p + bout[0];
}

extern "C" void kernel_launch(void* const* d_in, const int* in_sizes, int n_in,
                              void* d_out, int out_size, void* d_ws, size_t ws_size,
                              hipStream_t stream) {
  const float* enc_in   = (const float*)d_in[0];
  const float* dec_in   = (const float*)d_in[1];
  const float* ln_enc_g = (const float*)d_in[2];
  const float* ln_enc_b = (const float*)d_in[3];
  const float* W_enc    = (const float*)d_in[4];
  const float* U_enc    = (const float*)d_in[5];
  const float* b_enc    = (const float*)d_in[6];
  const float* W_dec    = (const float*)d_in[7];
  const float* U_dec    = (const float*)d_in[8];
  const float* b_dec    = (const float*)d_in[9];
  const float* Wq = (const float*)d_in[10]; const float* bq = (const float*)d_in[11];
  const float* Wk = (const float*)d_in[12]; const float* bk = (const float*)d_in[13];
  const float* Wv = (const float*)d_in[14]; const float* bv = (const float*)d_in[15];
  const float* Wo = (const float*)d_in[16]; const float* bo = (const float*)d_in[17];
  const float* ln_post_g = (const float*)d_in[18];
  const float* ln_post_b = (const float*)d_in[19];
  const float* W_out     = (const float*)d_in[20];
  const float* b_out     = (const float*)d_in[21];

  char* ws = (char*)d_ws;
  size_t off = 0;
  auto alloc = [&](size_t bytes) -> void* {
    void* p = ws + off;
    off += (bytes + 255) & ~(size_t)255;
    return p;
  };
  float* xln     = (float*)alloc((size_t)NBATCH * TENC * 8 * 4);
  uint4* upkE    = (uint4*)alloc((size_t)KQ * GDIM * 16);
  uint4* upkD    = (uint4*)alloc((size_t)KQ * GDIM * 16);
  float* enc_seq = (float*)alloc((size_t)NBATCH * TENC * 256 * 4);
  float* dec_seq = (float*)alloc((size_t)NBATCH * TDEC * 256 * 4);
  float* hfin    = (float*)alloc((size_t)NBATCH * 256 * 4);
  float* cfin    = (float*)alloc((size_t)NBATCH * 256 * 4);
  float* Qp      = (float*)alloc((size_t)NBATCH * NHEAD * TDEC * 32 * 4);
  u16*   Kb      = (u16*)  alloc((size_t)NBATCH * NHEAD * TENC * 32 * 2);
  u16*   Vb      = (u16*)  alloc((size_t)NBATCH * NHEAD * TENC * 32 * 2);
  float* ctx     = (float*)alloc((size_t)NBATCH * TDEC * 256 * 4);
  float* ctxo    = (float*)alloc((size_t)NBATCH * TDEC * 256 * 4);

  // 1. LN on encoder input
  k_ln8<<<dim3(256), dim3(256), 0, stream>>>(enc_in, ln_enc_g, ln_enc_b, xln,
                                             NBATCH * TENC);
  // 2. pack [U;W] -> per-column quad-major f16 pairs [33][1024]
  k_packUW3<<<dim3(132), dim3(256), 0, stream>>>(U_enc, W_enc, upkE);
  k_packUW3<<<dim3(132), dim3(256), 0, stream>>>(U_dec, W_dec, upkD);
  // 3. encoder scan
  k_scan11<<<dim3(NBATCH), dim3(512), 0, stream>>>(
      xln, upkE, b_enc, nullptr, nullptr, enc_seq, hfin, cfin, TENC);
  // 4. decoder scan
  k_scan11<<<dim3(NBATCH), dim3(512), 0, stream>>>(
      dec_in, upkD, b_dec, hfin, cfin, dec_seq, nullptr, nullptr, TDEC);
  // 5. projections
  k_gemm256<1><<<dim3(256, 4), dim3(256), 0, stream>>>(dec_seq, Wq, bq, Qp, NBATCH * TDEC, TDEC);
  k_gemm256<2><<<dim3(1024, 4), dim3(256), 0, stream>>>(enc_seq, Wk, bk, Kb, NBATCH * TENC, TENC);
  k_gemm256<2><<<dim3(1024, 4), dim3(256), 0, stream>>>(enc_seq, Wv, bv, Vb, NBATCH * TENC, TENC);
  // 6. attention
  k_attn<<<dim3(NBATCH * NHEAD), dim3(256), 0, stream>>>(Qp, Kb, Vb, ctx);
  // 7. output projection
  k_gemm256<0><<<dim3(256, 4), dim3(256), 0, stream>>>(ctx, Wo, bo, ctxo, NBATCH * TDEC, 0x7fffffff);
  // 8. residual + LN + final dot
  k_final<<<dim3(NBATCH * TDEC / 4), dim3(256), 0, stream>>>(
      dec_seq, ctxo, ln_post_g, ln_post_b, W_out, b_out, (float*)d_out);
}